// Round 1
// baseline (305.817 us; speedup 1.0000x reference)
//
#include <hip/hip_runtime.h>
#include <math.h>

#define NH 32
#define NKV 8
#define HD 128
#define HDIM 4096
#define KVDIM 1024
#define TPREV 16383
#define NCHUNK 64
#define CHUNK 256

// ws layout (floats)
#define OFF_Q 0
#define OFF_K 4096
#define OFF_V 5120
#define OFF_PART 6144
#define PART_STRIDE 130
#define OFF_CTX (OFF_PART + NH * NCHUNK * PART_STRIDE)   // 272384

__device__ __forceinline__ float wave_reduce_sum(float v) {
#pragma unroll
  for (int m = 32; m >= 1; m >>= 1) v += __shfl_xor(v, m, 64);
  return v;
}

// ---------------------------------------------------------------------------
// Kernel 1: fused QKV matvec + RoPE. 2 adjacent rows per block so the RoPE
// (even,odd) pair is entirely in-block. rows 0..4095 -> q, 4096..5119 -> k,
// 5120..6143 -> v (ws offsets coincide with the global row index).
// ---------------------------------------------------------------------------
__global__ __launch_bounds__(256) void qkv_rope_kernel(
    const float* __restrict__ Wq, const float* __restrict__ Wk,
    const float* __restrict__ Wv, const float* __restrict__ hidden,
    const int* __restrict__ pos_p, float* __restrict__ ws) {
  int r0 = blockIdx.x * 2;
  const float* W;
  int wr;
  if (r0 < HDIM) {
    W = Wq; wr = r0;
  } else if (r0 < HDIM + KVDIM) {
    W = Wk; wr = r0 - HDIM;
  } else {
    W = Wv; wr = r0 - HDIM - KVDIM;
  }
  const float4* w0 = (const float4*)(W + (size_t)wr * HDIM);
  const float4* w1 = (const float4*)(W + (size_t)(wr + 1) * HDIM);
  const float4* h4 = (const float4*)hidden;
  int t = threadIdx.x;
  float s0 = 0.f, s1 = 0.f;
#pragma unroll
  for (int k = 0; k < 4; ++k) {
    int idx = t + 256 * k;
    float4 b = h4[idx];
    float4 a0 = w0[idx];
    float4 a1 = w1[idx];
    s0 += a0.x * b.x + a0.y * b.y + a0.z * b.z + a0.w * b.w;
    s1 += a1.x * b.x + a1.y * b.y + a1.z * b.z + a1.w * b.w;
  }
  s0 = wave_reduce_sum(s0);
  s1 = wave_reduce_sum(s1);
  __shared__ float redA[4], redB[4];
  if ((t & 63) == 0) {
    redA[t >> 6] = s0;
    redB[t >> 6] = s1;
  }
  __syncthreads();
  if (t == 0) {
    float S0 = redA[0] + redA[1] + redA[2] + redA[3];
    float S1 = redB[0] + redB[1] + redB[2] + redB[3];
    if (r0 < HDIM + KVDIM) {
      // RoPE: pair index within the head; fp64 angle for accuracy at pos=16383
      int j = (r0 & (HD - 1)) >> 1;
      double f = (double)(*pos_p) * pow(10000.0, -(double)j / 64.0);
      float c = (float)cos(f), sn = (float)sin(f);
      ws[r0] = S0 * c - S1 * sn;
      ws[r0 + 1] = S0 * sn + S1 * c;
    } else {
      ws[r0] = S0;
      ws[r0 + 1] = S1;
    }
  }
}

// ---------------------------------------------------------------------------
// Kernel 2: flash-decoding chunks. Block = (kv head g, chunk c of 256 tokens).
// Computes scores for the 4 GQA q-heads of g, chunk-local softmax (max, exp,
// sum), weighted V accumulation. Writes partials acc[128], m, l per head.
// ---------------------------------------------------------------------------
__global__ __launch_bounds__(256) void attn_chunk_kernel(
    const float* __restrict__ k_cache, const float* __restrict__ v_cache,
    float* __restrict__ ws) {
  int g = blockIdx.x / NCHUNK;
  int c = blockIdx.x % NCHUNK;
  int t0 = c * CHUNK;
  int ntok = TPREV - t0;
  if (ntok > CHUNK) ntok = CHUNK;
  int tid = threadIdx.x;

  __shared__ float qs[4 * HD];      // 4 q-heads
  __shared__ float sc[CHUNK * 5];   // scores, stride 5 => conflict-free
  __shared__ float wredm[4][4], wredl[4][4];
  __shared__ float mh[4], lh[4];

  for (int i = tid; i < 4 * HD; i += 256) qs[i] = ws[OFF_Q + (g * 4) * HD + i];
  __syncthreads();

  const float rscale = 0.08838834764831845f;  // 1/sqrt(128)
  int grp = tid >> 5, lane = tid & 31;

  // --- scores: each 32-lane group handles one token per iteration ---
  for (int it = grp; it < CHUNK; it += 8) {
    int t = t0 + it;
    if (t < TPREV) {
      float4 kv = ((const float4*)(k_cache + (size_t)t * (NKV * HD) + g * HD))[lane];
      float4 q0 = ((const float4*)(qs + 0 * HD))[lane];
      float4 q1 = ((const float4*)(qs + 1 * HD))[lane];
      float4 q2 = ((const float4*)(qs + 2 * HD))[lane];
      float4 q3 = ((const float4*)(qs + 3 * HD))[lane];
      float s0 = kv.x * q0.x + kv.y * q0.y + kv.z * q0.z + kv.w * q0.w;
      float s1 = kv.x * q1.x + kv.y * q1.y + kv.z * q1.z + kv.w * q1.w;
      float s2 = kv.x * q2.x + kv.y * q2.y + kv.z * q2.z + kv.w * q2.w;
      float s3 = kv.x * q3.x + kv.y * q3.y + kv.z * q3.z + kv.w * q3.w;
#pragma unroll
      for (int m = 16; m >= 1; m >>= 1) {  // masks <=16 stay within 32-lane half
        s0 += __shfl_xor(s0, m, 64);
        s1 += __shfl_xor(s1, m, 64);
        s2 += __shfl_xor(s2, m, 64);
        s3 += __shfl_xor(s3, m, 64);
      }
      if (lane == 0) {
        sc[it * 5 + 0] = s0 * rscale;
        sc[it * 5 + 1] = s1 * rscale;
        sc[it * 5 + 2] = s2 * rscale;
        sc[it * 5 + 3] = s3 * rscale;
      }
    } else {
      if (lane == 0) {
        sc[it * 5 + 0] = -1e30f;
        sc[it * 5 + 1] = -1e30f;
        sc[it * 5 + 2] = -1e30f;
        sc[it * 5 + 3] = -1e30f;
      }
    }
  }
  __syncthreads();

  // --- chunk max per head (256 rows, 1 per thread) ---
  float m0 = sc[tid * 5 + 0], m1 = sc[tid * 5 + 1];
  float m2 = sc[tid * 5 + 2], m3 = sc[tid * 5 + 3];
#pragma unroll
  for (int m = 32; m >= 1; m >>= 1) {
    m0 = fmaxf(m0, __shfl_xor(m0, m, 64));
    m1 = fmaxf(m1, __shfl_xor(m1, m, 64));
    m2 = fmaxf(m2, __shfl_xor(m2, m, 64));
    m3 = fmaxf(m3, __shfl_xor(m3, m, 64));
  }
  if ((tid & 63) == 0) {
    int w = tid >> 6;
    wredm[w][0] = m0; wredm[w][1] = m1; wredm[w][2] = m2; wredm[w][3] = m3;
  }
  __syncthreads();
  if (tid < 4)
    mh[tid] = fmaxf(fmaxf(wredm[0][tid], wredm[1][tid]),
                    fmaxf(wredm[2][tid], wredm[3][tid]));
  __syncthreads();

  // --- exp + sum ---
  float M0 = mh[0], M1 = mh[1], M2 = mh[2], M3 = mh[3];
  float e0 = expf(sc[tid * 5 + 0] - M0);
  float e1 = expf(sc[tid * 5 + 1] - M1);
  float e2 = expf(sc[tid * 5 + 2] - M2);
  float e3 = expf(sc[tid * 5 + 3] - M3);
  sc[tid * 5 + 0] = e0;
  sc[tid * 5 + 1] = e1;
  sc[tid * 5 + 2] = e2;
  sc[tid * 5 + 3] = e3;
  float l0 = wave_reduce_sum(e0);
  float l1 = wave_reduce_sum(e1);
  float l2 = wave_reduce_sum(e2);
  float l3 = wave_reduce_sum(e3);
  if ((tid & 63) == 0) {
    int w = tid >> 6;
    wredl[w][0] = l0; wredl[w][1] = l1; wredl[w][2] = l2; wredl[w][3] = l3;
  }
  __syncthreads();
  if (tid < 4)
    lh[tid] = wredl[0][tid] + wredl[1][tid] + wredl[2][tid] + wredl[3][tid];
  __syncthreads();

  // --- V accumulation: thread owns (h0, d) and (h0+2, d) ---
  int d = tid & (HD - 1);
  int h0 = tid >> 7;  // 0 or 1
  const float* vp = v_cache + (size_t)t0 * (NKV * HD) + g * HD + d;
  float a0 = 0.f, a1 = 0.f;
  for (int it = 0; it < ntok; ++it) {
    float v = vp[(size_t)it * (NKV * HD)];
    a0 = fmaf(sc[it * 5 + h0], v, a0);
    a1 = fmaf(sc[it * 5 + h0 + 2], v, a1);
  }
  float* part = ws + OFF_PART;
  part[(size_t)((g * 4 + h0) * NCHUNK + c) * PART_STRIDE + d] = a0;
  part[(size_t)((g * 4 + h0 + 2) * NCHUNK + c) * PART_STRIDE + d] = a1;
  if (tid < 4) {
    part[(size_t)((g * 4 + tid) * NCHUNK + c) * PART_STRIDE + 128] = mh[tid];
    part[(size_t)((g * 4 + tid) * NCHUNK + c) * PART_STRIDE + 129] = lh[tid];
  }
}

// ---------------------------------------------------------------------------
// Kernel 3: combine partials + the new token (k/v from kernel 1) per q head.
// ---------------------------------------------------------------------------
__global__ __launch_bounds__(128) void combine_kernel(float* __restrict__ ws) {
  int h = blockIdx.x;
  int g = h >> 2;
  int d = threadIdx.x;
  const float rscale = 0.08838834764831845f;

  __shared__ float red[HD];
  red[d] = ws[OFF_Q + h * HD + d] * ws[OFF_K + g * HD + d];
  __syncthreads();
#pragma unroll
  for (int s = 64; s >= 1; s >>= 1) {
    if (d < s) red[d] += red[d + s];
    __syncthreads();
  }
  float snew = red[0] * rscale;

  const float* ph = ws + OFF_PART + (size_t)h * NCHUNK * PART_STRIDE;
  float M = snew;
  for (int c = 0; c < NCHUNK; ++c) M = fmaxf(M, ph[c * PART_STRIDE + 128]);
  float en = expf(snew - M);
  float L = en;
  float acc = en * ws[OFF_V + g * HD + d];
  for (int c = 0; c < NCHUNK; ++c) {
    float w = expf(ph[c * PART_STRIDE + 128] - M);
    L += ph[c * PART_STRIDE + 129] * w;
    acc += ph[c * PART_STRIDE + d] * w;
  }
  ws[OFF_CTX + h * HD + d] = acc / L;
}

// ---------------------------------------------------------------------------
// Kernel 4: out = Wo @ ctx. Same 2-rows-per-block matvec, no RoPE.
// ---------------------------------------------------------------------------
__global__ __launch_bounds__(256) void out_matvec_kernel(
    const float* __restrict__ Wo, const float* __restrict__ ws,
    float* __restrict__ out) {
  int r0 = blockIdx.x * 2;
  const float4* w0 = (const float4*)(Wo + (size_t)r0 * HDIM);
  const float4* w1 = (const float4*)(Wo + (size_t)(r0 + 1) * HDIM);
  const float4* x4 = (const float4*)(ws + OFF_CTX);
  int t = threadIdx.x;
  float s0 = 0.f, s1 = 0.f;
#pragma unroll
  for (int k = 0; k < 4; ++k) {
    int idx = t + 256 * k;
    float4 b = x4[idx];
    float4 a0 = w0[idx];
    float4 a1 = w1[idx];
    s0 += a0.x * b.x + a0.y * b.y + a0.z * b.z + a0.w * b.w;
    s1 += a1.x * b.x + a1.y * b.y + a1.z * b.z + a1.w * b.w;
  }
  s0 = wave_reduce_sum(s0);
  s1 = wave_reduce_sum(s1);
  __shared__ float redA[4], redB[4];
  if ((t & 63) == 0) {
    redA[t >> 6] = s0;
    redB[t >> 6] = s1;
  }
  __syncthreads();
  if (t == 0) {
    out[r0] = redA[0] + redA[1] + redA[2] + redA[3];
    out[r0 + 1] = redB[0] + redB[1] + redB[2] + redB[3];
  }
}

extern "C" void kernel_launch(void* const* d_in, const int* in_sizes, int n_in,
                              void* d_out, int out_size, void* d_ws,
                              size_t ws_size, hipStream_t stream) {
  const float* hidden = (const float*)d_in[0];
  const float* k_cache = (const float*)d_in[1];
  const float* v_cache = (const float*)d_in[2];
  const float* Wq = (const float*)d_in[3];
  const float* Wk = (const float*)d_in[4];
  const float* Wv = (const float*)d_in[5];
  const float* Wo = (const float*)d_in[6];
  const int* pos = (const int*)d_in[7];
  float* out = (float*)d_out;
  float* ws = (float*)d_ws;

  qkv_rope_kernel<<<(HDIM + KVDIM + KVDIM) / 2, 256, 0, stream>>>(
      Wq, Wk, Wv, hidden, pos, ws);
  attn_chunk_kernel<<<NKV * NCHUNK, 256, 0, stream>>>(k_cache, v_cache, ws);
  combine_kernel<<<NH, 128, 0, stream>>>(ws);
  out_matvec_kernel<<<HDIM / 2, 256, 0, stream>>>(Wo, ws, out);
}

// Round 2
// 290.679 us; speedup vs baseline: 1.0521x; 1.0521x over previous
//
#include <hip/hip_runtime.h>
#include <math.h>

#define NH 32
#define NKV 8
#define HD 128
#define HDIM 4096
#define KVDIM 1024
#define TPREV 16383
#define NCHUNK 128
#define CHUNK 128

// ws layout (floats)
#define OFF_Q 0
#define OFF_K 4096
#define OFF_V 5120
#define OFF_PART 6144
#define PART_STRIDE 130
#define OFF_CTX (OFF_PART + NH * NCHUNK * PART_STRIDE)  // 538624, 16B-aligned

__device__ __forceinline__ float wave_reduce_sum(float v) {
#pragma unroll
  for (int m = 32; m >= 1; m >>= 1) v += __shfl_xor(v, m, 64);
  return v;
}
__device__ __forceinline__ float wave_reduce_max(float v) {
#pragma unroll
  for (int m = 32; m >= 1; m >>= 1) v = fmaxf(v, __shfl_xor(v, m, 64));
  return v;
}

// ---------------------------------------------------------------------------
// Kernel 1: fused QKV matvec + RoPE. One row per 64-lane wave, 4 rows/block.
// Rows 0..4095 -> q, 4096..5119 -> k, 5120..6143 -> v (ws offset == row id).
// ---------------------------------------------------------------------------
__global__ __launch_bounds__(256) void qkv_rope_kernel(
    const float* __restrict__ Wq, const float* __restrict__ Wk,
    const float* __restrict__ Wv, const float* __restrict__ hidden,
    const int* __restrict__ pos_p, float* __restrict__ ws) {
  int r = blockIdx.x * 4 + (threadIdx.x >> 6);
  int lane = threadIdx.x & 63;
  const float* W;
  int wr;
  if (r < HDIM) {
    W = Wq; wr = r;
  } else if (r < HDIM + KVDIM) {
    W = Wk; wr = r - HDIM;
  } else {
    W = Wv; wr = r - HDIM - KVDIM;
  }
  const float4* w4 = (const float4*)(W + (size_t)wr * HDIM);
  const float4* h4 = (const float4*)hidden;
  float s = 0.f;
#pragma unroll
  for (int i = 0; i < 16; ++i) {
    float4 a = w4[lane + 64 * i];
    float4 b = h4[lane + 64 * i];
    s += a.x * b.x + a.y * b.y + a.z * b.z + a.w * b.w;
  }
  s = wave_reduce_sum(s);
  __shared__ float rs[4];
  if (lane == 0) rs[threadIdx.x >> 6] = s;
  __syncthreads();
  if (threadIdx.x < 2) {
    int r0 = blockIdx.x * 4 + (int)threadIdx.x * 2;
    float S0 = rs[threadIdx.x * 2], S1 = rs[threadIdx.x * 2 + 1];
    if (r0 < HDIM + KVDIM) {
      // fp64 angle: at pos=16383 fp32 angle error (~1e-3 rad) would breach tol
      int j = (r0 & (HD - 1)) >> 1;
      double f = (double)(*pos_p) * pow(10000.0, -(double)j / 64.0);
      float c = (float)cos(f), sn = (float)sin(f);
      ws[r0] = S0 * c - S1 * sn;
      ws[r0 + 1] = S0 * sn + S1 * c;
    } else {
      ws[r0] = S0;
      ws[r0 + 1] = S1;
    }
  }
}

// ---------------------------------------------------------------------------
// Kernel 2: flash-decoding chunks. Block = (kv head g, 128-token chunk c).
// Phase A: scores via 32-lane groups (1 token/group/iter), chunk softmax.
// Phase B: V accumulation — 8 token-groups x 32 lanes, float4 V loads,
//          4 heads x float4 dims in registers, LDS cross-group reduce.
// ---------------------------------------------------------------------------
__global__ __launch_bounds__(256) void attn_chunk_kernel(
    const float* __restrict__ k_cache, const float* __restrict__ v_cache,
    float* __restrict__ ws) {
  int g = blockIdx.x >> 7;   // NCHUNK = 128
  int c = blockIdx.x & 127;
  int t0 = c * CHUNK;
  int tid = threadIdx.x;

  __shared__ float qs[4 * HD];
  __shared__ float sc[CHUNK * 5];  // stride 5 -> conflict-free
  __shared__ float vacc[8][4][HD]; // 16 KB
  __shared__ float wredm[4][4], wredl[4][4];
  __shared__ float mh[4], lh[4];

  for (int i = tid; i < 4 * HD; i += 256) qs[i] = ws[OFF_Q + g * 4 * HD + i];
  __syncthreads();

  const float rscale = 0.08838834764831845f;  // 1/sqrt(128)
  int grp = tid >> 5, lane = tid & 31;

  // --- Phase A: scores ---
  for (int it = grp; it < CHUNK; it += 8) {
    int t = t0 + it;
    if (t < TPREV) {
      float4 kv = ((const float4*)(k_cache + (size_t)t * KVDIM + g * HD))[lane];
      float4 q0 = ((const float4*)(qs + 0 * HD))[lane];
      float4 q1 = ((const float4*)(qs + 1 * HD))[lane];
      float4 q2 = ((const float4*)(qs + 2 * HD))[lane];
      float4 q3 = ((const float4*)(qs + 3 * HD))[lane];
      float s0 = kv.x * q0.x + kv.y * q0.y + kv.z * q0.z + kv.w * q0.w;
      float s1 = kv.x * q1.x + kv.y * q1.y + kv.z * q1.z + kv.w * q1.w;
      float s2 = kv.x * q2.x + kv.y * q2.y + kv.z * q2.z + kv.w * q2.w;
      float s3 = kv.x * q3.x + kv.y * q3.y + kv.z * q3.z + kv.w * q3.w;
#pragma unroll
      for (int m = 16; m >= 1; m >>= 1) {  // masks <=16 stay in 32-lane half
        s0 += __shfl_xor(s0, m, 64);
        s1 += __shfl_xor(s1, m, 64);
        s2 += __shfl_xor(s2, m, 64);
        s3 += __shfl_xor(s3, m, 64);
      }
      if (lane == 0) {
        sc[it * 5 + 0] = s0 * rscale;
        sc[it * 5 + 1] = s1 * rscale;
        sc[it * 5 + 2] = s2 * rscale;
        sc[it * 5 + 3] = s3 * rscale;
      }
    } else if (lane == 0) {
      sc[it * 5 + 0] = -1e30f;
      sc[it * 5 + 1] = -1e30f;
      sc[it * 5 + 2] = -1e30f;
      sc[it * 5 + 3] = -1e30f;
    }
  }
  __syncthreads();

  // --- chunk max per head (rows 0..127; tid>=128 contributes -inf) ---
  float m0 = -1e30f, m1 = -1e30f, m2 = -1e30f, m3 = -1e30f;
  if (tid < CHUNK) {
    m0 = sc[tid * 5 + 0]; m1 = sc[tid * 5 + 1];
    m2 = sc[tid * 5 + 2]; m3 = sc[tid * 5 + 3];
  }
  m0 = wave_reduce_max(m0); m1 = wave_reduce_max(m1);
  m2 = wave_reduce_max(m2); m3 = wave_reduce_max(m3);
  if ((tid & 63) == 0) {
    int w = tid >> 6;
    wredm[w][0] = m0; wredm[w][1] = m1; wredm[w][2] = m2; wredm[w][3] = m3;
  }
  __syncthreads();
  if (tid < 4)
    mh[tid] = fmaxf(fmaxf(wredm[0][tid], wredm[1][tid]),
                    fmaxf(wredm[2][tid], wredm[3][tid]));
  __syncthreads();

  // --- exp + sum ---
  float M0 = mh[0], M1 = mh[1], M2 = mh[2], M3 = mh[3];
  float e0 = 0.f, e1 = 0.f, e2 = 0.f, e3 = 0.f;
  if (tid < CHUNK) {
    e0 = expf(sc[tid * 5 + 0] - M0);
    e1 = expf(sc[tid * 5 + 1] - M1);
    e2 = expf(sc[tid * 5 + 2] - M2);
    e3 = expf(sc[tid * 5 + 3] - M3);
    sc[tid * 5 + 0] = e0;
    sc[tid * 5 + 1] = e1;
    sc[tid * 5 + 2] = e2;
    sc[tid * 5 + 3] = e3;
  }
  float l0 = wave_reduce_sum(e0);
  float l1 = wave_reduce_sum(e1);
  float l2 = wave_reduce_sum(e2);
  float l3 = wave_reduce_sum(e3);
  if ((tid & 63) == 0) {
    int w = tid >> 6;
    wredl[w][0] = l0; wredl[w][1] = l1; wredl[w][2] = l2; wredl[w][3] = l3;
  }
  __syncthreads();
  if (tid < 4)
    lh[tid] = wredl[0][tid] + wredl[1][tid] + wredl[2][tid] + wredl[3][tid];
  __syncthreads();

  // --- Phase B: V accumulation, float4 loads, 16 regs of accumulators ---
  float4 a0 = {0, 0, 0, 0}, a1 = {0, 0, 0, 0}, a2 = {0, 0, 0, 0},
         a3 = {0, 0, 0, 0};
  for (int it = grp; it < CHUNK; it += 8) {
    int t = t0 + it;
    if (t < TPREV) {
      float4 v = ((const float4*)(v_cache + (size_t)t * KVDIM + g * HD))[lane];
      float p0 = sc[it * 5 + 0], p1 = sc[it * 5 + 1];
      float p2 = sc[it * 5 + 2], p3 = sc[it * 5 + 3];
      a0.x = fmaf(p0, v.x, a0.x); a0.y = fmaf(p0, v.y, a0.y);
      a0.z = fmaf(p0, v.z, a0.z); a0.w = fmaf(p0, v.w, a0.w);
      a1.x = fmaf(p1, v.x, a1.x); a1.y = fmaf(p1, v.y, a1.y);
      a1.z = fmaf(p1, v.z, a1.z); a1.w = fmaf(p1, v.w, a1.w);
      a2.x = fmaf(p2, v.x, a2.x); a2.y = fmaf(p2, v.y, a2.y);
      a2.z = fmaf(p2, v.z, a2.z); a2.w = fmaf(p2, v.w, a2.w);
      a3.x = fmaf(p3, v.x, a3.x); a3.y = fmaf(p3, v.y, a3.y);
      a3.z = fmaf(p3, v.z, a3.z); a3.w = fmaf(p3, v.w, a3.w);
    }
  }
  ((float4*)&vacc[grp][0][0])[lane] = a0;
  ((float4*)&vacc[grp][1][0])[lane] = a1;
  ((float4*)&vacc[grp][2][0])[lane] = a2;
  ((float4*)&vacc[grp][3][0])[lane] = a3;
  __syncthreads();

  // --- cross-group reduce + global write of partials ---
  float* part = ws + OFF_PART;
#pragma unroll
  for (int rep = 0; rep < 2; ++rep) {
    int p = tid + rep * 256;          // p in [0,512): h = p>>7, d = p&127
    int h = p >> 7, d = p & 127;
    float s = 0.f;
#pragma unroll
    for (int g2 = 0; g2 < 8; ++g2) s += vacc[g2][h][d];
    part[(size_t)((g * 4 + h) * NCHUNK + c) * PART_STRIDE + d] = s;
  }
  if (tid < 4) {
    part[(size_t)((g * 4 + tid) * NCHUNK + c) * PART_STRIDE + 128] = mh[tid];
    part[(size_t)((g * 4 + tid) * NCHUNK + c) * PART_STRIDE + 129] = lh[tid];
  }
}

// ---------------------------------------------------------------------------
// Kernel 3: combine 128 partials + new token per q head. 256 threads.
// Weights precomputed into LDS so the acc loop is pure independent FMA+load.
// ---------------------------------------------------------------------------
__global__ __launch_bounds__(256) void combine_kernel(float* __restrict__ ws) {
  int h = blockIdx.x;
  int g = h >> 2;
  int tid = threadIdx.x;
  const float rscale = 0.08838834764831845f;
  const float* ph = ws + OFF_PART + (size_t)h * NCHUNK * PART_STRIDE;

  __shared__ float red[HD];
  __shared__ float wexp[NCHUNK];
  __shared__ float wm[4], wl[4];
  __shared__ float acc2[HD];

  // dot(q_h, k_new)
  if (tid < HD) red[tid] = ws[OFF_Q + h * HD + tid] * ws[OFF_K + g * HD + tid];
  __syncthreads();
#pragma unroll
  for (int s2 = 64; s2 >= 1; s2 >>= 1) {
    if (tid < s2 && tid + s2 < HD) red[tid] += red[tid + s2];
    __syncthreads();
  }
  float snew = red[0] * rscale;

  // global max over chunk maxima + snew
  float mloc = -1e30f;
  if (tid < NCHUNK) {
    mloc = ph[tid * PART_STRIDE + 128];
    wexp[tid] = mloc;  // stash m
  }
  float mm = wave_reduce_max(fmaxf(mloc, snew));
  if ((tid & 63) == 0) wm[tid >> 6] = mm;
  __syncthreads();
  float M = fmaxf(fmaxf(wm[0], wm[1]), fmaxf(wm[2], wm[3]));

  // weights + denominator
  float lpart = 0.f;
  if (tid < NCHUNK) {
    float w = expf(wexp[tid] - M);
    lpart = ph[tid * PART_STRIDE + 129] * w;
    wexp[tid] = w;
  }
  float lsum = wave_reduce_sum(lpart);
  if ((tid & 63) == 0) wl[tid >> 6] = lsum;
  __syncthreads();
  float en = expf(snew - M);
  float L = wl[0] + wl[1] + wl[2] + wl[3] + en;

  // accumulate: 2 chunk-halves x 128 dims
  int half = tid >> 7, d = tid & 127;
  float acc = 0.f;
  int cbeg = half * 64;
#pragma unroll 4
  for (int c2 = cbeg; c2 < cbeg + 64; ++c2)
    acc = fmaf(ph[(size_t)c2 * PART_STRIDE + d], wexp[c2], acc);
  if (half == 0) acc2[d] = acc;
  __syncthreads();
  if (half == 1) acc2[d] += acc;
  __syncthreads();
  if (tid < HD)
    ws[OFF_CTX + h * HD + tid] =
        (acc2[tid] + en * ws[OFF_V + g * HD + tid]) / L;
}

// ---------------------------------------------------------------------------
// Kernel 4: out = Wo @ ctx. One row per wave, 4 rows/block, no LDS/barriers.
// ---------------------------------------------------------------------------
__global__ __launch_bounds__(256) void out_matvec_kernel(
    const float* __restrict__ Wo, const float* __restrict__ ws,
    float* __restrict__ out) {
  int r = blockIdx.x * 4 + (threadIdx.x >> 6);
  int lane = threadIdx.x & 63;
  const float4* w4 = (const float4*)(Wo + (size_t)r * HDIM);
  const float4* x4 = (const float4*)(ws + OFF_CTX);
  float s = 0.f;
#pragma unroll
  for (int i = 0; i < 16; ++i) {
    float4 a = w4[lane + 64 * i];
    float4 b = x4[lane + 64 * i];
    s += a.x * b.x + a.y * b.y + a.z * b.z + a.w * b.w;
  }
  s = wave_reduce_sum(s);
  if (lane == 0) out[r] = s;
}

extern "C" void kernel_launch(void* const* d_in, const int* in_sizes, int n_in,
                              void* d_out, int out_size, void* d_ws,
                              size_t ws_size, hipStream_t stream) {
  const float* hidden = (const float*)d_in[0];
  const float* k_cache = (const float*)d_in[1];
  const float* v_cache = (const float*)d_in[2];
  const float* Wq = (const float*)d_in[3];
  const float* Wk = (const float*)d_in[4];
  const float* Wv = (const float*)d_in[5];
  const float* Wo = (const float*)d_in[6];
  const int* pos = (const int*)d_in[7];
  float* out = (float*)d_out;
  float* ws = (float*)d_ws;

  qkv_rope_kernel<<<(HDIM + 2 * KVDIM) / 4, 256, 0, stream>>>(Wq, Wk, Wv,
                                                              hidden, pos, ws);
  attn_chunk_kernel<<<NKV * NCHUNK, 256, 0, stream>>>(k_cache, v_cache, ws);
  combine_kernel<<<NH, 256, 0, stream>>>(ws);
  out_matvec_kernel<<<HDIM / 4, 256, 0, stream>>>(Wo, ws, out);
}

// Round 3
// 286.940 us; speedup vs baseline: 1.0658x; 1.0130x over previous
//
#include <hip/hip_runtime.h>
#include <math.h>

#define NH 32
#define NKV 8
#define HD 128
#define HDIM 4096
#define KVDIM 1024
#define TPREV 16383
#define NCHUNK 64
#define CHUNK 256

// ws layout (floats)
#define OFF_Q 0
#define OFF_K 4096
#define OFF_V 5120
#define OFF_PART 6144
#define PART_STRIDE 130
#define OFF_CTX (OFF_PART + NH * NCHUNK * PART_STRIDE)  // 272384, 16B-aligned

__device__ __forceinline__ float wave_reduce_sum(float v) {
#pragma unroll
  for (int m = 32; m >= 1; m >>= 1) v += __shfl_xor(v, m, 64);
  return v;
}
__device__ __forceinline__ float wave_reduce_max(float v) {
#pragma unroll
  for (int m = 32; m >= 1; m >>= 1) v = fmaxf(v, __shfl_xor(v, m, 64));
  return v;
}
__device__ __forceinline__ float dot4(float4 a, float4 b) {
  return a.x * b.x + a.y * b.y + a.z * b.z + a.w * b.w;
}

// ---------------------------------------------------------------------------
// Kernel 1: fused QKV matvec + RoPE. One row per 64-lane wave, 4 rows/block.
// 8-deep load batches force MLP (8 KB W-bytes in flight per wave).
// ---------------------------------------------------------------------------
__global__ __launch_bounds__(256) void qkv_rope_kernel(
    const float* __restrict__ Wq, const float* __restrict__ Wk,
    const float* __restrict__ Wv, const float* __restrict__ hidden,
    const int* __restrict__ pos_p, float* __restrict__ ws) {
  int r = blockIdx.x * 4 + (threadIdx.x >> 6);
  int lane = threadIdx.x & 63;
  const float* W;
  int wr;
  if (r < HDIM) {
    W = Wq; wr = r;
  } else if (r < HDIM + KVDIM) {
    W = Wk; wr = r - HDIM;
  } else {
    W = Wv; wr = r - HDIM - KVDIM;
  }
  const float4* w4 = (const float4*)(W + (size_t)wr * HDIM);
  const float4* h4 = (const float4*)hidden;
  float s = 0.f;
#pragma unroll
  for (int base = 0; base < 16; base += 8) {
    float4 a[8], b[8];
#pragma unroll
    for (int j = 0; j < 8; ++j) a[j] = w4[lane + 64 * (base + j)];
#pragma unroll
    for (int j = 0; j < 8; ++j) b[j] = h4[lane + 64 * (base + j)];
#pragma unroll
    for (int j = 0; j < 8; ++j) s += dot4(a[j], b[j]);
  }
  s = wave_reduce_sum(s);
  __shared__ float rs[4];
  if (lane == 0) rs[threadIdx.x >> 6] = s;
  __syncthreads();
  if (threadIdx.x < 2) {
    int r0 = blockIdx.x * 4 + (int)threadIdx.x * 2;
    float S0 = rs[threadIdx.x * 2], S1 = rs[threadIdx.x * 2 + 1];
    if (r0 < HDIM + KVDIM) {
      // fp64 angle: fp32 angle at pos=16383 has ~1e-3 rad error -> breach tol
      int j = (r0 & (HD - 1)) >> 1;
      double f = (double)(*pos_p) * pow(10000.0, -(double)j / 64.0);
      float c = (float)cos(f), sn = (float)sin(f);
      ws[r0] = S0 * c - S1 * sn;
      ws[r0 + 1] = S0 * sn + S1 * c;
    } else {
      ws[r0] = S0;
      ws[r0 + 1] = S1;
    }
  }
}

// ---------------------------------------------------------------------------
// Kernel 2: flash-decoding chunks. Block = (kv head g, 256-token chunk c).
// Phase A: THREAD-PER-TOKEN scores — each thread streams its token's 512B
//          K-row in 8-deep float4 batches; q broadcast from LDS; no shuffles.
// Phase B: 8 token-groups x 32 lanes, 4-deep batched float4 V loads.
// ---------------------------------------------------------------------------
__global__ __launch_bounds__(256, 2) void attn_chunk_kernel(
    const float* __restrict__ k_cache, const float* __restrict__ v_cache,
    float* __restrict__ ws) {
  int g = blockIdx.x >> 6;  // NCHUNK = 64
  int c = blockIdx.x & 63;
  int t0 = c * CHUNK;
  int tid = threadIdx.x;

  __shared__ float qs[4 * HD];       // 2 KB
  __shared__ float sc[CHUNK * 5];    // 5 KB, stride 5 -> conflict-free writes
  __shared__ float vacc[8][4][HD];   // 16 KB
  __shared__ float wredm[4][4], wredl[4][4];
  __shared__ float mh[4], lh[4];

  for (int i = tid; i < 4 * HD; i += 256) qs[i] = ws[OFF_Q + g * 4 * HD + i];
  __syncthreads();

  const float rscale = 0.08838834764831845f;  // 1/sqrt(128)

  // --- Phase A: scores, one token per thread ---
  int tok = t0 + tid;
  bool valid = tok < TPREV;
  float s0 = -1e30f, s1 = -1e30f, s2 = -1e30f, s3 = -1e30f;
  if (valid) {
    const float4* kp = (const float4*)(k_cache + (size_t)tok * KVDIM + g * HD);
    const float4* q4 = (const float4*)qs;  // head h at index h*32 + i
    s0 = 0.f; s1 = 0.f; s2 = 0.f; s3 = 0.f;
#pragma unroll
    for (int base = 0; base < 32; base += 8) {
      float4 kk[8];
#pragma unroll
      for (int j = 0; j < 8; ++j) kk[j] = kp[base + j];
#pragma unroll
      for (int j = 0; j < 8; ++j) {
        s0 += dot4(kk[j], q4[0 * 32 + base + j]);
        s1 += dot4(kk[j], q4[1 * 32 + base + j]);
        s2 += dot4(kk[j], q4[2 * 32 + base + j]);
        s3 += dot4(kk[j], q4[3 * 32 + base + j]);
      }
    }
    s0 *= rscale; s1 *= rscale; s2 *= rscale; s3 *= rscale;
  }

  // --- block max per head ---
  float m0 = wave_reduce_max(s0), m1 = wave_reduce_max(s1);
  float m2 = wave_reduce_max(s2), m3 = wave_reduce_max(s3);
  if ((tid & 63) == 0) {
    int w = tid >> 6;
    wredm[w][0] = m0; wredm[w][1] = m1; wredm[w][2] = m2; wredm[w][3] = m3;
  }
  __syncthreads();
  if (tid < 4)
    mh[tid] = fmaxf(fmaxf(wredm[0][tid], wredm[1][tid]),
                    fmaxf(wredm[2][tid], wredm[3][tid]));
  __syncthreads();

  // --- exp + sum (masked threads: s=-1e30 -> e=0) ---
  float e0 = expf(s0 - mh[0]), e1 = expf(s1 - mh[1]);
  float e2 = expf(s2 - mh[2]), e3 = expf(s3 - mh[3]);
  sc[tid * 5 + 0] = e0;
  sc[tid * 5 + 1] = e1;
  sc[tid * 5 + 2] = e2;
  sc[tid * 5 + 3] = e3;
  float l0 = wave_reduce_sum(e0), l1 = wave_reduce_sum(e1);
  float l2 = wave_reduce_sum(e2), l3 = wave_reduce_sum(e3);
  if ((tid & 63) == 0) {
    int w = tid >> 6;
    wredl[w][0] = l0; wredl[w][1] = l1; wredl[w][2] = l2; wredl[w][3] = l3;
  }
  __syncthreads();
  if (tid < 4)
    lh[tid] = wredl[0][tid] + wredl[1][tid] + wredl[2][tid] + wredl[3][tid];
  __syncthreads();

  // --- Phase B: V accumulation, 4-deep batched float4 loads ---
  int grp = tid >> 5, lane = tid & 31;
  float4 a0 = {0, 0, 0, 0}, a1 = {0, 0, 0, 0}, a2 = {0, 0, 0, 0},
         a3 = {0, 0, 0, 0};
  const float4 z4 = {0, 0, 0, 0};
#pragma unroll
  for (int base = 0; base < 32; base += 4) {
    float4 vv[4];
#pragma unroll
    for (int j = 0; j < 4; ++j) {
      int it = grp + 8 * (base + j);
      int t = t0 + it;
      vv[j] = (t < TPREV)
                  ? ((const float4*)(v_cache + (size_t)t * KVDIM + g * HD))[lane]
                  : z4;
    }
#pragma unroll
    for (int j = 0; j < 4; ++j) {
      int it = grp + 8 * (base + j);
      float p0 = sc[it * 5 + 0], p1 = sc[it * 5 + 1];
      float p2 = sc[it * 5 + 2], p3 = sc[it * 5 + 3];
      a0.x = fmaf(p0, vv[j].x, a0.x); a0.y = fmaf(p0, vv[j].y, a0.y);
      a0.z = fmaf(p0, vv[j].z, a0.z); a0.w = fmaf(p0, vv[j].w, a0.w);
      a1.x = fmaf(p1, vv[j].x, a1.x); a1.y = fmaf(p1, vv[j].y, a1.y);
      a1.z = fmaf(p1, vv[j].z, a1.z); a1.w = fmaf(p1, vv[j].w, a1.w);
      a2.x = fmaf(p2, vv[j].x, a2.x); a2.y = fmaf(p2, vv[j].y, a2.y);
      a2.z = fmaf(p2, vv[j].z, a2.z); a2.w = fmaf(p2, vv[j].w, a2.w);
      a3.x = fmaf(p3, vv[j].x, a3.x); a3.y = fmaf(p3, vv[j].y, a3.y);
      a3.z = fmaf(p3, vv[j].z, a3.z); a3.w = fmaf(p3, vv[j].w, a3.w);
    }
  }
  ((float4*)&vacc[grp][0][0])[lane] = a0;
  ((float4*)&vacc[grp][1][0])[lane] = a1;
  ((float4*)&vacc[grp][2][0])[lane] = a2;
  ((float4*)&vacc[grp][3][0])[lane] = a3;
  __syncthreads();

  // --- cross-group reduce + global write of partials ---
  float* part = ws + OFF_PART;
#pragma unroll
  for (int rep = 0; rep < 2; ++rep) {
    int p = tid + rep * 256;  // p in [0,512): h = p>>7, d = p&127
    int h = p >> 7, d = p & 127;
    float s = 0.f;
#pragma unroll
    for (int g2 = 0; g2 < 8; ++g2) s += vacc[g2][h][d];
    part[(size_t)((g * 4 + h) * NCHUNK + c) * PART_STRIDE + d] = s;
  }
  if (tid < 4) {
    part[(size_t)((g * 4 + tid) * NCHUNK + c) * PART_STRIDE + 128] = mh[tid];
    part[(size_t)((g * 4 + tid) * NCHUNK + c) * PART_STRIDE + 129] = lh[tid];
  }
}

// ---------------------------------------------------------------------------
// Kernel 3: combine 64 partials + new token per q head. 256 threads.
// ---------------------------------------------------------------------------
__global__ __launch_bounds__(256) void combine_kernel(float* __restrict__ ws) {
  int h = blockIdx.x;
  int g = h >> 2;
  int tid = threadIdx.x;
  const float rscale = 0.08838834764831845f;
  const float* ph = ws + OFF_PART + (size_t)h * NCHUNK * PART_STRIDE;

  __shared__ float red[HD];
  __shared__ float wexp[NCHUNK];
  __shared__ float Msh, Lsh;
  __shared__ float acc2[HD];

  // dot(q_h, k_new)
  if (tid < HD) red[tid] = ws[OFF_Q + h * HD + tid] * ws[OFF_K + g * HD + tid];
  __syncthreads();
#pragma unroll
  for (int s2 = 64; s2 >= 1; s2 >>= 1) {
    if (tid < s2 && tid + s2 < HD) red[tid] += red[tid + s2];
    __syncthreads();
  }
  float snew = red[0] * rscale;

  // wave 0 handles all 64 chunk (m,l) pairs
  if (tid < 64) {
    float m = ph[tid * PART_STRIDE + 128];
    float M = wave_reduce_max(fmaxf(m, snew));
    float w = expf(m - M);
    float lp = ph[tid * PART_STRIDE + 129] * w;
    float L = wave_reduce_sum(lp);
    wexp[tid] = w;
    if (tid == 0) { Msh = M; Lsh = L; }
  }
  __syncthreads();
  float M = Msh;
  float en = expf(snew - M);
  float L = Lsh + en;

  // accumulate: 2 chunk-halves x 128 dims, 32 iters each
  int half = tid >> 7, d = tid & 127;
  float acc = 0.f;
  int cbeg = half * 32;
#pragma unroll 8
  for (int c2 = cbeg; c2 < cbeg + 32; ++c2)
    acc = fmaf(ph[(size_t)c2 * PART_STRIDE + d], wexp[c2], acc);
  if (half == 0) acc2[d] = acc;
  __syncthreads();
  if (half == 1) acc2[d] += acc;
  __syncthreads();
  if (tid < HD)
    ws[OFF_CTX + h * HD + tid] =
        (acc2[tid] + en * ws[OFF_V + g * HD + tid]) / L;
}

// ---------------------------------------------------------------------------
// Kernel 4: out = Wo @ ctx. One row per wave, batched loads, no barriers.
// ---------------------------------------------------------------------------
__global__ __launch_bounds__(256) void out_matvec_kernel(
    const float* __restrict__ Wo, const float* __restrict__ ws,
    float* __restrict__ out) {
  int r = blockIdx.x * 4 + (threadIdx.x >> 6);
  int lane = threadIdx.x & 63;
  const float4* w4 = (const float4*)(Wo + (size_t)r * HDIM);
  const float4* x4 = (const float4*)(ws + OFF_CTX);
  float s = 0.f;
#pragma unroll
  for (int base = 0; base < 16; base += 8) {
    float4 a[8], b[8];
#pragma unroll
    for (int j = 0; j < 8; ++j) a[j] = w4[lane + 64 * (base + j)];
#pragma unroll
    for (int j = 0; j < 8; ++j) b[j] = x4[lane + 64 * (base + j)];
#pragma unroll
    for (int j = 0; j < 8; ++j) s += dot4(a[j], b[j]);
  }
  s = wave_reduce_sum(s);
  if (lane == 0) out[r] = s;
}

extern "C" void kernel_launch(void* const* d_in, const int* in_sizes, int n_in,
                              void* d_out, int out_size, void* d_ws,
                              size_t ws_size, hipStream_t stream) {
  const float* hidden = (const float*)d_in[0];
  const float* k_cache = (const float*)d_in[1];
  const float* v_cache = (const float*)d_in[2];
  const float* Wq = (const float*)d_in[3];
  const float* Wk = (const float*)d_in[4];
  const float* Wv = (const float*)d_in[5];
  const float* Wo = (const float*)d_in[6];
  const int* pos = (const int*)d_in[7];
  float* out = (float*)d_out;
  float* ws = (float*)d_ws;

  qkv_rope_kernel<<<(HDIM + 2 * KVDIM) / 4, 256, 0, stream>>>(Wq, Wk, Wv,
                                                              hidden, pos, ws);
  attn_chunk_kernel<<<NKV * NCHUNK, 256, 0, stream>>>(k_cache, v_cache, ws);
  combine_kernel<<<NH, 256, 0, stream>>>(ws);
  out_matvec_kernel<<<HDIM / 4, 256, 0, stream>>>(Wo, ws, out);
}